// Round 3
// baseline (401.365 us; speedup 1.0000x reference)
//
#include <hip/hip_runtime.h>

// ---------- problem constants ----------
#define CDIM   768
#define NSEQ   196
#define NVIEW  5
#define BN_TOT 6272       // B*N
#define SLAB   4816896    // BN_TOT*CDIM
#define WSLAB  589824     // CDIM*CDIM

typedef __attribute__((ext_vector_type(8))) short short8;  // 8 bf16 (4 VGPRs)
typedef __attribute__((ext_vector_type(4))) float f32x4;

// ---------- helpers ----------
__device__ __forceinline__ float bf_lo(unsigned u) { return __uint_as_float(u << 16); }
__device__ __forceinline__ float bf_hi(unsigned u) { return __uint_as_float(u & 0xffff0000u); }
__device__ __forceinline__ unsigned short f2bf(float f) {
  unsigned u = __float_as_uint(f);
  return (unsigned short)((u + 0x7fffu + ((u >> 16) & 1u)) >> 16);  // RNE
}
__device__ __forceinline__ unsigned pack2(float f0, float f1) {
  return (unsigned)f2bf(f0) | ((unsigned)f2bf(f1) << 16);
}
__device__ __forceinline__ float ftanh(float x) {
  x = fminf(fmaxf(x, -10.f), 10.f);
  float e = __expf(2.f * x);
  return (e - 1.f) / (e + 1.f);
}
__device__ __forceinline__ void async_cp16(const void* g, void* l) {
  __builtin_amdgcn_global_load_lds((const __attribute__((address_space(1))) unsigned*)g,
                                   (__attribute__((address_space(3))) unsigned*)l, 16, 0, 0);
}

// ---------- weight transpose fp32 -> bf16: 7 matrices of 768x768 (+ plain bf16 wv copy) ----------
__global__ __launch_bounds__(256) void k_tr(const float* __restrict__ wv,
                                            const float* __restrict__ w1,
                                            unsigned short* __restrict__ wvT,
                                            unsigned short* __restrict__ w1aT,
                                            unsigned short* __restrict__ w1bT,
                                            unsigned short* __restrict__ wvB) {
  __shared__ float tile[32][33];
  const int m = blockIdx.z;
  const float* src;
  unsigned short* dst;
  unsigned short* dstB = nullptr;
  if (m < NVIEW)      { src = wv + (size_t)m * WSLAB; dst = wvT + (size_t)m * WSLAB;
                        dstB = wvB + (size_t)m * WSLAB; }
  else if (m == NVIEW){ src = w1;                     dst = w1aT; }
  else                { src = w1 + WSLAB;             dst = w1bT; }
  const int tx = threadIdx.x, ty = threadIdx.y;
  const int x0 = blockIdx.x * 32, y0 = blockIdx.y * 32;
#pragma unroll
  for (int i = 0; i < 4; ++i) {
    float v = src[(size_t)(y0 + ty + i * 8) * CDIM + x0 + tx];
    tile[ty + i * 8][tx] = v;
    if (dstB) dstB[(size_t)(y0 + ty + i * 8) * CDIM + x0 + tx] = f2bf(v);
  }
  __syncthreads();
#pragma unroll
  for (int i = 0; i < 4; ++i)
    dst[(size_t)(x0 + ty + i * 8) * CDIM + y0 + tx] = f2bf(tile[tx][ty + i * 8]);
}

// ---------- cb = bf16(mean over v of x) ----------
__global__ __launch_bounds__(192) void k_mean(const float* __restrict__ x,
                                              unsigned short* __restrict__ cb) {
  const int bn = blockIdx.x;
  const int b = bn / NSEQ, n = bn % NSEQ;
  const int h = threadIdx.x * 4;
  const float* xp = x + ((size_t)(b * NVIEW) * NSEQ + n) * CDIM + h;
  float s0 = 0, s1 = 0, s2 = 0, s3 = 0;
#pragma unroll
  for (int v = 0; v < NVIEW; ++v) {
    float4 p = *(const float4*)(xp + (size_t)v * (NSEQ * CDIM));
    s0 += p.x; s1 += p.y; s2 += p.z; s3 += p.w;
  }
  uint2 o;
  o.x = pack2(s0 * 0.2f, s1 * 0.2f);
  o.y = pack2(s2 * 0.2f, s3 * 0.2f);
  *(uint2*)(cb + (size_t)bn * CDIM + h) = o;
}

// ---------- 128x256-tile 8-wave MFMA GEMM, 2-ring LDS, 2 blocks/CU ----------
// (resubmission of round-2 kernel: container-level infra failure, source
//  re-audited — no OOB / no barrier divergence / swizzle ledger consistent)
// 8 waves 2(M)x4(N), 64x64 out each -> acc 64 VGPR; __launch_bounds__(512,4)
// caps regs at 128 -> 2 blocks/CU (2 x 48 KiB LDS). One barrier + one full
// vmcnt drain per K-tile; the drain of one block hides under the other
// block's MFMA (m97/m114 mechanism: block-TLP fills the pipeline gaps).
// LDS XOR swizzle (chunk ^= (row>>1)&3) applied on the pre-swizzled GLOBAL
// source of global_load_lds AND on the ds_read address (both-sides, rule 21);
// the fp32-A path applies it on the ds_write address instead (reg-staged).
// MODE 0 (2205 works = 5v x 49mt x 9nt): A = x[:,v,:,:] fp32 (reg-convert
//   staging); nt/3 selects Bt/C triple: wvT_v->projb_v | w1aT->xw1b_v |
//   wpT_v->pw1b_v (pw1b = x@(wv@w1b), linearity fusion kills old GEMM B).
// MODE 1 (90 works): wpT_v = w1bT @ wvB_v^T  (i.e. (wv@w1b)^T, M=768).
// MODE 2 (147 works): cw1 = cb @ w1bT.
template <int MODE>
__global__ __launch_bounds__(512, 4) void gemm_f(const float* __restrict__ X,
                                                 const unsigned short* __restrict__ P0,
                                                 const unsigned short* __restrict__ P1,
                                                 const unsigned short* __restrict__ P2,
                                                 unsigned short* __restrict__ Q0,
                                                 unsigned short* __restrict__ Q1,
                                                 unsigned short* __restrict__ Q2) {
  __shared__ __align__(16) unsigned short lds[2 * 12288];  // 2 slots x (A 4096 + B 8192) shorts
  constexpr int NWG = (MODE == 0) ? 2205 : (MODE == 1) ? 90 : 147;
  constexpr int NKT = CDIM / 32;   // 24
  // bijective XCD swizzle (m204 form)
  const int orig = blockIdx.x;
  const int qq = NWG >> 3, rr = NWG & 7, xcd = orig & 7, slot = orig >> 3;
  const int wk = (xcd < rr ? xcd * (qq + 1) : rr * (qq + 1) + (xcd - rr) * qq) + slot;

  const int t = threadIdx.x, w = t >> 6, lane = t & 63, lr = lane & 15, lq = lane >> 4;
  const int wm = ((w >> 2) & 1) * 64;   // 0 / 64
  const int wn = (w & 3) * 64;          // 0 / 64 / 128 / 192

  const unsigned short* Abf = nullptr;
  const unsigned short* Bt;
  unsigned short* C;
  const float* aPtr = nullptr;
  int colBase, mrow0;
  if constexpr (MODE == 0) {
    const int v = wk / 441, rem = wk % 441;
    const int mt = rem / 9, nt = rem % 9;
    const int sub = nt / 3, ntl = nt % 3;
    Bt = (sub == 0) ? P0 + (size_t)v * WSLAB : (sub == 1) ? P1 : P2 + (size_t)v * WSLAB;
    C  = (sub == 0) ? Q0 + (size_t)v * SLAB  : (sub == 1) ? Q1 + (size_t)v * SLAB
                                             : Q2 + (size_t)v * SLAB;
    colBase = ntl * 256; mrow0 = mt * 128;
    const int r = mrow0 + (t >> 2);
    const int b = r / 196, n = r - b * 196;
    aPtr = X + (size_t)((b * 5 + v) * 196 + n) * CDIM + (t & 3) * 8;
  } else if constexpr (MODE == 1) {
    const int v = wk / 18, rem = wk % 18;
    const int mt = rem / 3, nt = rem % 3;
    Abf = P0;                          // w1bT
    Bt  = P2 + (size_t)v * WSLAB;      // wvB_v
    C   = Q0 + (size_t)v * WSLAB;      // wpT_v
    colBase = nt * 256; mrow0 = mt * 128;
  } else {
    const int mt = wk / 3, nt = wk % 3;
    Abf = P1;                          // cb
    Bt  = P0;                          // w1bT
    C   = Q0;                          // cw1
    colBase = nt * 256; mrow0 = mt * 128;
  }

  // staging sources (pre-swizzled k-chunk; global_load_lds dest is linear)
  const int swz = ((t & 3) ^ ((t >> 3) & 3)) << 3;
  const unsigned short* gBp = Bt + (size_t)(colBase + (t >> 2)) * CDIM + swz;
  const unsigned short* gAb = (MODE == 0) ? nullptr
                            : Abf + (size_t)(mrow0 + (t >> 2)) * CDIM + swz;
  const int aswz = swz;  // fp32-A path: write-side swizzle (same involution)

  // ds_read addressing (chunk = lq ^ ((lr>>1)&3), matches source swizzle)
  const int kch = ((lq ^ ((lr >> 1) & 3)) << 3);

#define STB(kt, s) { const unsigned short* sp_ = gBp + (kt) * 32;                 \
    unsigned short* dp_ = lds + (s) * 12288 + 4096 + (w << 9);                    \
    async_cp16(sp_, dp_); async_cp16(sp_ + (size_t)128 * CDIM, dp_ + 4096); }
#define STA1(kt, s) { async_cp16(gAb + (kt) * 32, lds + (s) * 12288 + (w << 9)); }
#define STA0W(s) { uint4 qv_;                                                     \
    qv_.x = pack2(pa0.x, pa0.y); qv_.y = pack2(pa0.z, pa0.w);                     \
    qv_.z = pack2(pa1.x, pa1.y); qv_.w = pack2(pa1.z, pa1.w);                     \
    *(uint4*)(lds + (s) * 12288 + (t >> 2) * 32 + aswz) = qv_; }

  f32x4 acc[4][4] = {};
  float4 pa0{}, pa1{};

  // ---- prologue: stage K-tile 0 into slot 0 ----
  if constexpr (MODE == 0) { pa0 = *(const float4*)(aPtr); pa1 = *(const float4*)(aPtr + 4); }
  else                     { STA1(0, 0); }
  STB(0, 0);
  if constexpr (MODE == 0) STA0W(0);
  asm volatile("s_waitcnt vmcnt(0) lgkmcnt(0)" ::: "memory");
  __builtin_amdgcn_s_barrier();

  for (int kt = 0; kt < NKT; ++kt) {
    const int s = kt & 1;
    const unsigned short* bp = lds + s * 12288;
    const bool pf = (kt + 1 < NKT);
    if (pf) {   // issue next tile early: fp32 A loads + B DMA into the free slot
      if constexpr (MODE == 0) {
        pa0 = *(const float4*)(aPtr + (kt + 1) * 32);
        pa1 = *(const float4*)(aPtr + (kt + 1) * 32 + 4);
      } else { STA1(kt + 1, s ^ 1); }
      STB(kt + 1, s ^ 1);
    }
    short8 af[4], bf[4];
#pragma unroll
    for (int i = 0; i < 4; ++i) af[i] = *(const short8*)(bp + (wm + i * 16 + lr) * 32 + kch);
#pragma unroll
    for (int j = 0; j < 4; ++j) bf[j] = *(const short8*)(bp + 4096 + (wn + j * 16 + lr) * 32 + kch);
    __builtin_amdgcn_s_setprio(1);
#pragma unroll
    for (int i = 0; i < 4; ++i)
#pragma unroll
      for (int j = 0; j < 4; ++j)
        acc[i][j] = __builtin_amdgcn_mfma_f32_16x16x32_bf16(af[i], bf[j], acc[i][j], 0, 0, 0);
    __builtin_amdgcn_s_setprio(0);
    if (pf) { if constexpr (MODE == 0) STA0W(s ^ 1); }   // a-loads had the MFMA window to land
    asm volatile("s_waitcnt vmcnt(0) lgkmcnt(0)" ::: "memory");
    __builtin_amdgcn_s_barrier();
  }
#undef STB
#undef STA1
#undef STA0W

  // ---- epilogue (no M-tail: all MODEs have M % 128 == 0) ----
#pragma unroll
  for (int i = 0; i < 4; ++i)
#pragma unroll
    for (int j = 0; j < 4; ++j) {
      const int gr = mrow0 + wm + i * 16 + lq * 4;   // C/D: row=(lane>>4)*4+reg, col=lane&15
      const int gc = colBase + wn + j * 16 + lr;
      unsigned short* cp = C + (size_t)gr * CDIM + gc;
#pragma unroll
      for (int r = 0; r < 4; ++r)
        cp[(size_t)r * CDIM] = f2bf(acc[i][j][r]);
    }
}

// ---------- fully fused routing loop: 3x (scores -> softmax -> weighted sum), pointwise in bn ----------
__global__ __launch_bounds__(192) void k_iter3(const unsigned short* __restrict__ xw1b,
                                               const unsigned short* __restrict__ cw1,
                                               const unsigned short* __restrict__ pw1b,
                                               const unsigned short* __restrict__ projb,
                                               const float* __restrict__ b1,
                                               const float* __restrict__ w2,
                                               float* __restrict__ outc,
                                               float* __restrict__ outr) {
  __shared__ float red[3][NVIEW];
  __shared__ float aa[NVIEW];
  const int bn = blockIdx.x, t = threadIdx.x, wid = t >> 6, lane = t & 63;
  const int h = t * 4;
  const float4 bv = *(const float4*)(b1 + h);
  const float4 wv = *(const float4*)(w2 + h);
  float cw[4];
  { uint2 c = *(const uint2*)(cw1 + (size_t)bn * CDIM + h);
    cw[0] = bf_lo(c.x); cw[1] = bf_hi(c.x); cw[2] = bf_lo(c.y); cw[3] = bf_hi(c.y); }
  float xw[NVIEW][4], pf[NVIEW][4];
#pragma unroll
  for (int v = 0; v < NVIEW; ++v) {
    uint2 q = *(const uint2*)(xw1b + ((size_t)v * BN_TOT + bn) * CDIM + h);
    xw[v][0] = bf_lo(q.x) + bv.x; xw[v][1] = bf_hi(q.x) + bv.y;
    xw[v][2] = bf_lo(q.y) + bv.z; xw[v][3] = bf_hi(q.y) + bv.w;
    uint2 p = *(const uint2*)(pw1b + ((size_t)v * BN_TOT + bn) * CDIM + h);
    pf[v][0] = bf_lo(p.x); pf[v][1] = bf_hi(p.x);
    pf[v][2] = bf_lo(p.y); pf[v][3] = bf_hi(p.y);
  }
  for (int it = 0; it < 3; ++it) {
    float part[NVIEW];
#pragma unroll
    for (int v = 0; v < NVIEW; ++v) {
      float p;
      p = wv.x * ftanh(xw[v][0] + cw[0]);
      p = fmaf(wv.y, ftanh(xw[v][1] + cw[1]), p);
      p = fmaf(wv.z, ftanh(xw[v][2] + cw[2]), p);
      p = fmaf(wv.w, ftanh(xw[v][3] + cw[3]), p);
      part[v] = p;
    }
#pragma unroll
    for (int off = 32; off > 0; off >>= 1)
#pragma unroll
      for (int v = 0; v < NVIEW; ++v) part[v] += __shfl_down(part[v], off);
    if (lane == 0)
#pragma unroll
      for (int v = 0; v < NVIEW; ++v) red[wid][v] = part[v];
    __syncthreads();
    if (t == 0) {
      float s[NVIEW];
#pragma unroll
      for (int v = 0; v < NVIEW; ++v) s[v] = red[0][v] + red[1][v] + red[2][v];
      float m = s[0];
#pragma unroll
      for (int v = 1; v < NVIEW; ++v) m = fmaxf(m, s[v]);
      float a[NVIEW], sum = 0.f;
#pragma unroll
      for (int v = 0; v < NVIEW; ++v) { a[v] = __expf(s[v] - m); sum += a[v]; }
      const float inv = 1.f / sum;
#pragma unroll
      for (int v = 0; v < NVIEW; ++v) { a[v] *= inv; aa[v] = a[v]; }
      if (it == 2) {
        float ent = 0.f;
#pragma unroll
        for (int v = 0; v < NVIEW; ++v) ent -= a[v] * logf(a[v] + 1e-8f);
        outr[bn] = 1.f - ent * 0.6213349345596119f;  // 1/ln(5)
      }
    }
    __syncthreads();
    if (it < 2) {
      float n0 = 0, n1 = 0, n2 = 0, n3 = 0;
#pragma unroll
      for (int v = 0; v < NVIEW; ++v) {
        const float av = aa[v];
        n0 = fmaf(av, pf[v][0], n0); n1 = fmaf(av, pf[v][1], n1);
        n2 = fmaf(av, pf[v][2], n2); n3 = fmaf(av, pf[v][3], n3);
      }
      cw[0] = n0; cw[1] = n1; cw[2] = n2; cw[3] = n3;
    } else {
      float r0 = 0, r1 = 0, r2 = 0, r3 = 0;
#pragma unroll
      for (int v = 0; v < NVIEW; ++v) {
        const float av = aa[v];
        uint2 p = *(const uint2*)(projb + ((size_t)v * BN_TOT + bn) * CDIM + h);
        r0 = fmaf(av, bf_lo(p.x), r0); r1 = fmaf(av, bf_hi(p.x), r1);
        r2 = fmaf(av, bf_lo(p.y), r2); r3 = fmaf(av, bf_hi(p.y), r3);
      }
      float4 of; of.x = r0; of.y = r1; of.z = r2; of.w = r3;
      *(float4*)(outc + (size_t)bn * CDIM + h) = of;
    }
  }
}

extern "C" void kernel_launch(void* const* d_in, const int* in_sizes, int n_in,
                              void* d_out, int out_size, void* d_ws, size_t ws_size,
                              hipStream_t stream) {
  (void)in_sizes; (void)n_in; (void)out_size; (void)ws_size;
  const float* x  = (const float*)d_in[0];   // [B,V,N,C] fp32
  const float* wv = (const float*)d_in[1];   // [V,C,C]
  const float* w1 = (const float*)d_in[2];   // [2C,H]
  const float* b1 = (const float*)d_in[3];   // [H]
  const float* w2 = (const float*)d_in[4];   // [H,1]
  // d_in[5] = b2: uniform shift over views -> softmax-invariant, unused.

  // workspace: 86,016,000 ushorts = 172 MB total (exactly the known-safe size)
  unsigned short* ws   = (unsigned short*)d_ws;
  unsigned short* wvT  = ws;                   //  2,949,120  Bt for proj
  unsigned short* w1aT = ws + 2949120;         //    589,824
  unsigned short* w1bT = ws + 3538944;         //    589,824
  unsigned short* projb= ws + 4128768;         // 24,084,480
  unsigned short* xw1b = ws + 28213248;        // 24,084,480
  unsigned short* wvB  = ws + 28213248;        //  2,949,120  (aliased: dead before xw1b written)
  unsigned short* pw1b = ws + 52297728;        // 24,084,480
  unsigned short* cb   = ws + 76382208;        //  4,816,896
  unsigned short* cw1  = ws + 81199104;        //  4,816,896  (end: 86,016,000)
  unsigned short* wpT  = ws + 81199104;        //  2,949,120  (aliased in cw1: dead before cw1 written)

  float* outc = (float*)d_out;                 // c [B,N,C] fp32
  float* outr = outc + SLAB;                   // r [B,N]   fp32

  k_tr<<<dim3(24, 24, 7), dim3(32, 8), 0, stream>>>(wv, w1, wvT, w1aT, w1bT, wvB);
  k_mean<<<BN_TOT, 192, 0, stream>>>(x, cb);
  // W' precompute: wpT_v = (wv_v @ w1b)^T, 90 blocks (~2 us)
  gemm_f<1><<<90, 512, 0, stream>>>(nullptr, w1bT, nullptr, wvB, wpT, nullptr, nullptr);
  // fused main GEMM: proj_v | xw1_v | pw1b_v  (15 slabs, 2205 blocks, 2 blocks/CU)
  gemm_f<0><<<2205, 512, 0, stream>>>(x, wvT, w1aT, wpT, projb, xw1b, pw1b);
  // cw1 = cb @ w1b (147 blocks; overwrites wpT region only after main GEMM done)
  gemm_f<2><<<147, 512, 0, stream>>>(nullptr, w1bT, cb, nullptr, cw1, nullptr, nullptr);
  // fused routing: 3 iterations pointwise in (b,n), no GEMMs (linearity of @w1b)
  k_iter3<<<BN_TOT, 192, 0, stream>>>(xw1b, cw1, pw1b, projb, b1, w2, outc, outr);
}